// Round 14
// baseline (77.492 us; speedup 1.0000x reference)
//
#include <hip/hip_runtime.h>

typedef unsigned short u16;
typedef unsigned int u32;
typedef __bf16 bf16x8 __attribute__((ext_vector_type(8)));
typedef float f32x4 __attribute__((ext_vector_type(4)));
typedef unsigned short u16x4 __attribute__((ext_vector_type(4)));

#define LOG2E 1.4426950408889634f

#if __has_builtin(__builtin_amdgcn_exp2f)
#define EXP2F(x) __builtin_amdgcn_exp2f(x)
#else
#define EXP2F(x) exp2f(x)
#endif

__device__ __forceinline__ u16 f2bf(float f) {
    union { float f; u32 u; } a; a.f = f;
    u32 u = a.u;
    u += 0x7FFFu + ((u >> 16) & 1u);   // RNE (finite inputs)
    return (u16)(u >> 16);
}
__device__ __forceinline__ bf16x8 ldg8(const u16* p) {
    return *reinterpret_cast<const bf16x8*>(p);
}
#if __has_builtin(__builtin_amdgcn_cvt_pk_bf16_f32)
__device__ __forceinline__ u32 pack2(float a, float b) {
    auto r = __builtin_amdgcn_cvt_pk_bf16_f32(a, b);   // v_cvt_pk_bf16_f32
    return __builtin_bit_cast(u32, r);
}
#else
__device__ __forceinline__ u32 pack2(float a, float b) {
    u32 ua = __float_as_uint(a) + 0x8000u;
    u32 ub = __float_as_uint(b) + 0x8000u;
    return __builtin_amdgcn_perm(ub, ua, 0x07060302);
}
#endif
// async global -> LDS, 16 B per lane. LDS dest = wave-uniform base + lane*16.
__device__ __forceinline__ void async16(const void* g, void* l) {
    __builtin_amdgcn_global_load_lds(
        (const __attribute__((address_space(1))) u32*)g,
        (__attribute__((address_space(3))) u32*)l, 16, 0, 0);
}

#define MFMA16(a, b, c) __builtin_amdgcn_mfma_f32_16x16x32_bf16((a), (b), (c), 0, 0, 0)

// ---------------------------------------------------------------------------
// Fused prep: y<8 -> transpose X tile; y in 8..11 -> pack weight matrix;
// y==12 -> lqw * log2(e) into global fp32 (4 blocks). Grid (64, 13).
// ---------------------------------------------------------------------------
__global__ __launch_bounds__(256) void prep(const float* __restrict__ X,
                                            u16* __restrict__ Xt,
                                            const float* __restrict__ s0,
                                            const float* __restrict__ s1,
                                            const float* __restrict__ s2,
                                            const float* __restrict__ s3,
                                            u16* __restrict__ Wqkv,
                                            u16* __restrict__ Wp,
                                            const float* __restrict__ lqw,
                                            float* __restrict__ lqw2g) {
    __shared__ u16 tile[64][65];
    const int tid = threadIdx.x;
    const int y = blockIdx.y;

    if (y < 8) {                                  // transpose 64x64 tile
        const int t0 = blockIdx.x * 64;
        const int c0 = y * 64;
#pragma unroll
        for (int i = 0; i < 16; ++i) {
            int idx = tid + i * 256;
            int r = idx >> 6, cc = idx & 63;
            tile[r][cc] = f2bf(X[(size_t)(c0 + r) * 4096 + t0 + cc]);
        }
        __syncthreads();
#pragma unroll
        for (int i = 0; i < 16; ++i) {
            int idx = tid + i * 256;
            int tr = idx >> 6, cc = idx & 63;
            Xt[(size_t)(t0 + tr) * 512 + c0 + cc] = tile[cc][tr];
        }
    } else if (y < 12) {                          // pack one 512x512 weight
        const int m = y - 8;
        const float* s = (m == 0) ? s0 : (m == 1) ? s1 : (m == 2) ? s2 : s3;
        u16* d = (m == 3) ? Wp : Wqkv + (size_t)m * 262144;
#pragma unroll
        for (int j = 0; j < 4; ++j) {
            int i = blockIdx.x * 1024 + j * 256 + tid;
            float4 v = reinterpret_cast<const float4*>(s)[i];
            u16x4 o;
            o[0] = f2bf(v.x); o[1] = f2bf(v.y); o[2] = f2bf(v.z); o[3] = f2bf(v.w);
            reinterpret_cast<u16x4*>(d)[i] = o;
        }
    } else {                                      // lqw * LOG2E (1024 float4)
        if (blockIdx.x < 4) {
            int i = blockIdx.x * 256 + tid;
            float4 v = reinterpret_cast<const float4*>(lqw)[i];
            v.x *= LOG2E; v.y *= LOG2E; v.z *= LOG2E; v.w *= LOG2E;
            reinterpret_cast<float4*>(lqw2g)[i] = v;
        }
    }
}

// ---------------------------------------------------------------------------
// Fused QKV GEMM, LDS-staged. Qt token-major (unchanged). K AND V are both
// written as FRAG-MAJOR images [head][tile][fragX][lane][8 u16] so the flash
// kernel reads every fragment as a fully-coalesced 1KB wave ldg8 on the
// regular load path (no LDS, no async, no swizzle in the consumer).
// K mapping (derived by composing the proven stage-swizzle with the A0/A1
// reads — the XORs cancel; 3 samples hand-verified):
//   Kimg slot (X, lane=quad*16+lm) = K[key=(X>>1)*16+lm][d=(X&1)*32+quad*8..+7]
// V mapping: R13-proven frag-major image (unchanged).
// ---------------------------------------------------------------------------
__global__ __launch_bounds__(512, 2) void qkv_gemm(const u16* __restrict__ Wqkv,
                                                   const u16* __restrict__ Xt,
                                                   const float* __restrict__ qb,
                                                   const float* __restrict__ kb,
                                                   const float* __restrict__ vb,
                                                   u16* __restrict__ Qt,
                                                   u16* __restrict__ Kimg,
                                                   u16* __restrict__ Vimg) {
    __shared__ __align__(16) u16 Al[2][128 * 32];
    __shared__ __align__(16) u16 Bl[2][128 * 32];

    const int tid = threadIdx.x;
    const int w = tid >> 6, lane = tid & 63;
    const int quad = lane >> 4, lm = lane & 15;
    const int wm = w & 1, wn = w >> 1;
    const int n0 = blockIdx.x * 128;
    const int my = blockIdx.y;
    const int m0 = my * 128;

    const int arow = lane >> 2;
    const int sch = (lane & 3) ^ ((lane >> 3) & 3);   // source chunk (XOR on row>>1)
    const u16* agp = Wqkv + (size_t)(m0 + w * 16 + arow) * 512 + sch * 8;
    const u16* bgp = Xt + (size_t)(n0 + w * 16 + arow) * 512 + sch * 8;

    async16(agp, &Al[0][w * 16 * 32]);
    async16(bgp, &Bl[0][w * 16 * 32]);
    agp += 32; bgp += 32;

    const int FOFF = lm * 64 + ((quad ^ ((lm >> 1) & 3)) << 4);

    f32x4 acc[4][2];
#pragma unroll
    for (int mt = 0; mt < 4; ++mt)
#pragma unroll
        for (int bt = 0; bt < 2; ++bt) acc[mt][bt] = (f32x4){0.f, 0.f, 0.f, 0.f};

    __syncthreads();

    for (int s = 0; s < 16; ++s) {
        const int buf = s & 1;
        if (s < 15) {
            async16(agp, &Al[buf ^ 1][w * 16 * 32]);
            async16(bgp, &Bl[buf ^ 1][w * 16 * 32]);
            agp += 32; bgp += 32;
        }
        const char* Ab = (const char*)&Al[buf][0];
        const char* Bb = (const char*)&Bl[buf][0];
        bf16x8 af[4], bfr[2];
#pragma unroll
        for (int mt = 0; mt < 4; ++mt)
            af[mt] = *(const bf16x8*)(Ab + wm * 4096 + mt * 1024 + FOFF);
#pragma unroll
        for (int bt = 0; bt < 2; ++bt)
            bfr[bt] = *(const bf16x8*)(Bb + wn * 2048 + bt * 1024 + FOFF);
#pragma unroll
        for (int mt = 0; mt < 4; ++mt)
#pragma unroll
            for (int bt = 0; bt < 2; ++bt)
                acc[mt][bt] = MFMA16(af[mt], bfr[bt], acc[mt][bt]);
        __syncthreads();
    }

    const int mat = my >> 2;                     // 0=Q, 1=K, 2=V
    const float* bias = (mat == 0) ? qb : (mat == 1) ? kb : vb;
    const int chbase = (my & 3) * 128 + wm * 64 + quad * 4;

    if (mat == 0) {
        const float sc = 0.125f * LOG2E;
#pragma unroll
        for (int mt = 0; mt < 4; ++mt) {
            const int ch = chbase + mt * 16;
            float4 bv = *(const float4*)(bias + ch);
            float bvf[4] = {bv.x, bv.y, bv.z, bv.w};
#pragma unroll
            for (int bt = 0; bt < 2; ++bt) {
                int tok = n0 + wn * 32 + bt * 16 + lm;
                u16x4 pk;
#pragma unroll
                for (int r = 0; r < 4; ++r)
                    pk[r] = f2bf((acc[mt][bt][r] + bvf[r]) * sc);
                *(u16x4*)(Qt + (size_t)tok * 512 + ch) = pk;
            }
        }
    } else if (mat == 1) {
        // K -> frag-major image
#pragma unroll
        for (int mt = 0; mt < 4; ++mt) {
            const int ch = chbase + mt * 16;
            float4 bv = *(const float4*)(bias + ch);
            float bvf[4] = {bv.x, bv.y, bv.z, bv.w};
            const int hh = ch >> 6;
            const int D0 = ch & 63;
            const int cq = (D0 >> 3) & 3;
            const int dh = D0 >> 5;
            const int e0 = D0 & 7;
#pragma unroll
            for (int bt = 0; bt < 2; ++bt) {
                int tok = n0 + wn * 32 + bt * 16 + lm;
                int t = tok >> 5;
                int kh = (tok >> 4) & 1;
                u16x4 pk;
#pragma unroll
                for (int r = 0; r < 4; ++r)
                    pk[r] = f2bf(acc[mt][bt][r] + bvf[r]);
                *(u16x4*)(Kimg + (size_t)(hh * 128 + t) * 2048 +
                          (kh * 2 + dh) * 512 + (cq * 16 + lm) * 8 + e0) = pk;
            }
        }
    } else {
        // V -> frag-major image (R13-proven)
#pragma unroll
        for (int mt = 0; mt < 4; ++mt) {
            const int ch = chbase + mt * 16;
            float4 bv = *(const float4*)(bias + ch);
            float bvf[4] = {bv.x, bv.y, bv.z, bv.w};
            const int hh = ch >> 6;
            const int D0 = ch & 63;
#pragma unroll
            for (int bt = 0; bt < 2; ++bt) {
                int g = bt * 16 + lm;
                int key2 = 8 * ((g >> 2) & 3) + 4 * ((g >> 4) & 1) + (g & 3);
                int t = (n0 >> 5) + wn;
                int kc = key2 >> 3, ke = key2 & 7;
                u16* vdst = Vimg + (size_t)(hh * 128 + t) * 2048 + ke;
#pragma unroll
                for (int r = 0; r < 4; ++r) {
                    int D = D0 + r;
                    int lane_i = kc * 16 + ((D >> 1) & 7) * 2 + (D & 1);
                    vdst[(size_t)(D >> 4) * 512 + lane_i * 8] = f2bf(acc[mt][bt][r] + bvf[r]);
                }
            }
        }
    }
}

// ---------------------------------------------------------------------------
// Output projection, LDS-staged (unchanged, known-good).
// ---------------------------------------------------------------------------
__global__ __launch_bounds__(256, 2) void out_gemm(const u16* __restrict__ Wp,
                                                   const u16* __restrict__ Ot,
                                                   const float* __restrict__ pb,
                                                   float* __restrict__ out) {
    __shared__ __align__(16) u16 Al[2][128 * 32];
    __shared__ __align__(16) u16 Bl[2][64 * 32];

    const int tid = threadIdx.x;
    const int w = tid >> 6, lane = tid & 63;
    const int quad = lane >> 4, lm = lane & 15;
    const int wm = w & 1, wn = w >> 1;
    const int n0 = blockIdx.x * 64;
    const int m0 = blockIdx.y * 128;

    const int arow = lane >> 2;
    const int sch = (lane & 3) ^ ((lane >> 3) & 3);
    const u16* agp0 = Wp + (size_t)(m0 + w * 16 + arow) * 512 + sch * 8;
    const u16* agp1 = agp0 + (size_t)64 * 512;
    const u16* bgp = Ot + (size_t)(n0 + w * 16 + arow) * 512 + sch * 8;

    async16(agp0, &Al[0][w * 16 * 32]);
    async16(agp1, &Al[0][(64 + w * 16) * 32]);
    async16(bgp, &Bl[0][w * 16 * 32]);
    agp0 += 32; agp1 += 32; bgp += 32;

    const int FOFF = lm * 64 + ((quad ^ ((lm >> 1) & 3)) << 4);

    f32x4 acc[4][2];
#pragma unroll
    for (int mt = 0; mt < 4; ++mt)
#pragma unroll
        for (int bt = 0; bt < 2; ++bt) acc[mt][bt] = (f32x4){0.f, 0.f, 0.f, 0.f};

    __syncthreads();

    for (int s = 0; s < 16; ++s) {
        const int buf = s & 1;
        if (s < 15) {
            async16(agp0, &Al[buf ^ 1][w * 16 * 32]);
            async16(agp1, &Al[buf ^ 1][(64 + w * 16) * 32]);
            async16(bgp, &Bl[buf ^ 1][w * 16 * 32]);
            agp0 += 32; agp1 += 32; bgp += 32;
        }
        const char* Ab = (const char*)&Al[buf][0];
        const char* Bb = (const char*)&Bl[buf][0];
        bf16x8 af[4], bfr[2];
#pragma unroll
        for (int mt = 0; mt < 4; ++mt)
            af[mt] = *(const bf16x8*)(Ab + wm * 4096 + mt * 1024 + FOFF);
#pragma unroll
        for (int bt = 0; bt < 2; ++bt)
            bfr[bt] = *(const bf16x8*)(Bb + wn * 2048 + bt * 1024 + FOFF);
#pragma unroll
        for (int mt = 0; mt < 4; ++mt)
#pragma unroll
            for (int bt = 0; bt < 2; ++bt)
                acc[mt][bt] = MFMA16(af[mt], bfr[bt], acc[mt][bt]);
        __syncthreads();
    }

#pragma unroll
    for (int mt = 0; mt < 4; ++mt) {
        const int ch = m0 + wm * 64 + mt * 16 + quad * 4;
        float4 bv = *(const float4*)(pb + ch);
        float bvf[4] = {bv.x, bv.y, bv.z, bv.w};
#pragma unroll
        for (int bt = 0; bt < 2; ++bt) {
            int tok = n0 + wn * 32 + bt * 16 + lm;
#pragma unroll
            for (int r = 0; r < 4; ++r)
                out[(size_t)(ch + r) * 4096 + tok] = acc[mt][bt][r] + bvf[r];
        }
    }
}

// ---------------------------------------------------------------------------
// Flash attention v15: ALL-DIRECT — no LDS staging, no async, no inline-asm
// waits in the main loop. R13 post-mortem: halving async traffic gained
// only 2 us -> the async path wasn't the binding resource. Remaining
// theories: (A) total-L2 ~11.5 TB/s for this mix; (B) in-wave latency from
// the ds_read/vmcnt machinery at 2 waves/SIMD. v15 discriminates: both K
// and V stream from frag-major pre-baked images via 8 coalesced 1KB ldg8
// per 32-key step, double-register-buffered (A/B alternation, 1-body
// prefetch distance, no copies); compiler inserts exact per-load vmcnt.
// Ones-row MFMA -> VALU psum (saves 20 regs; live ~218 <= 256 cap).
// Per step: 8 ldg8 + 8 QK MFMA + 16 exp2 + 8 pack + 16 PV MFMA.
// Everything else (head-clustered grid 512, 4 private key-quarter waves,
// 64 q/block, split-K=4 merge) unchanged. LDS = 54 KB merge buffer only.
// WRITE_SIZE ~4 MB is the spill sentinel; if flat at ~44 us, theory (A)
// confirmed -> declare ceiling.
// ---------------------------------------------------------------------------
__global__ __launch_bounds__(256, 2) void flash_attn(const u16* __restrict__ Qt,
                                                     const u16* __restrict__ Kimg,
                                                     const u16* __restrict__ Vimg,
                                                     const float* __restrict__ lqw2g,
                                                     u16* __restrict__ Ot) {
    __shared__ __align__(16) float smem[13600];      // 12288 mbuf + 1280 lbuf

    const int tid = threadIdx.x;
    const int w = tid >> 6, lane = tid & 63;         // w = 0..3 (key quarter)
    const int quad = lane >> 4, lm = lane & 15;
    const int bid = blockIdx.x;
    const int h = bid & 7, hq = h * 64;              // head -> XCD cluster
    const int q0 = (bid >> 3) * 64;
    const int kstart = w * 1024;

    // frag-major streams: tile = 2048 u16 (4 KB); frag X at +X*512; lane at +lane*8
    const u16* kp = Kimg + (size_t)(h * 128 + w * 32) * 2048 + (size_t)lane * 8;
    const u16* vp = Vimg + (size_t)(h * 128 + w * 32) * 2048 + (size_t)lane * 8;

    // Q fragments: 4 subtiles x 2 d-halves (8 vmem loads)
    bf16x8 bq0[4], bq1[4];
#pragma unroll
    for (int s = 0; s < 4; ++s) {
        const u16* qb = Qt + (size_t)(q0 + s * 16 + lm) * 512 + hq + quad * 8;
        bq0[s] = ldg8(qb);
        bq1[s] = ldg8(qb + 32);
    }

    // bias prefetch registers
    f32x4 breg0 = *(const f32x4*)(lqw2g + kstart + quad * 4);
    f32x4 breg1 = *(const f32x4*)(lqw2g + kstart + 16 + quad * 4);
    const float* bptr = lqw2g + kstart + 32 + quad * 4;

    f32x4 acc_o[4][4];                                // [d-group][q-sub]
#pragma unroll
    for (int mt = 0; mt < 4; ++mt)
#pragma unroll
        for (int s = 0; s < 4; ++s) acc_o[mt][s] = (f32x4){0.f, 0.f, 0.f, 0.f};
    float psum[4] = {0.f, 0.f, 0.f, 0.f};

    // double-register-buffered K and V streams
    bf16x8 kA0, kA1, kA2, kA3, kB0, kB1, kB2, kB3;
    bf16x8 vA0, vA1, vA2, vA3, vB0, vB1, vB2, vB3;
    union { u32 u[4]; bf16x8 v; } pb_[4];             // P of previous tile

    // prologue: K_0 -> kA
    kA0 = ldg8(kp); kA1 = ldg8(kp + 512); kA2 = ldg8(kp + 1024); kA3 = ldg8(kp + 1536);
    kp += 2048;

// body t: load V_t -> VN, K_{t+1} -> KN; PV_{t-1}(VC, pb_); QK_t(KC) -> pb_
#define BODY(KC0, KC1, KC2, KC3, KN0, KN1, KN2, KN3,                           \
             VC0, VC1, VC2, VC3, VN0, VN1, VN2, VN3, DOLDK, DOBIAS, DOPV)      \
    {                                                                          \
        VN0 = ldg8(vp); VN1 = ldg8(vp + 512);                                  \
        VN2 = ldg8(vp + 1024); VN3 = ldg8(vp + 1536);                          \
        vp += 2048;                                                            \
        if (DOLDK) {                                                           \
            KN0 = ldg8(kp); KN1 = ldg8(kp + 512);                              \
            KN2 = ldg8(kp + 1024); KN3 = ldg8(kp + 1536);                      \
            kp += 2048;                                                        \
        }                                                                      \
        if (DOPV) {                                                            \
            _Pragma("unroll")                                                  \
            for (int s = 0; s < 4; ++s) {                                      \
                acc_o[0][s] = MFMA16(VC0, pb_[s].v, acc_o[0][s]);              \
                acc_o[1][s] = MFMA16(VC1, pb_[s].v, acc_o[1][s]);              \
                acc_o[2][s] = MFMA16(VC2, pb_[s].v, acc_o[2][s]);              \
                acc_o[3][s] = MFMA16(VC3, pb_[s].v, acc_o[3][s]);              \
            }                                                                  \
        }                                                                      \
        _Pragma("unroll")                                                      \
        for (int s = 0; s < 4; ++s) {                                          \
            f32x4 a = MFMA16(KC0, bq0[s], breg0);                              \
            a = MFMA16(KC1, bq1[s], a);                                        \
            float e0 = EXP2F(a[0]), e1 = EXP2F(a[1]);                          \
            float e2 = EXP2F(a[2]), e3 = EXP2F(a[3]);                          \
            psum[s] += (e0 + e1) + (e2 + e3);                                  \
            pb_[s].u[0] = pack2(e0, e1);                                       \
            pb_[s].u[1] = pack2(e2, e3);                                       \
            f32x4 c = MFMA16(KC2, bq0[s], breg1);                              \
            c = MFMA16(KC3, bq1[s], c);                                        \
            float f0 = EXP2F(c[0]), f1 = EXP2F(c[1]);                          \
            float f2 = EXP2F(c[2]), f3 = EXP2F(c[3]);                          \
            psum[s] += (f0 + f1) + (f2 + f3);                                  \
            pb_[s].u[2] = pack2(f0, f1);                                       \
            pb_[s].u[3] = pack2(f2, f3);                                       \
        }                                                                      \
        if (DOBIAS) {                                                          \
            breg0 = *(const f32x4*)(bptr);                                     \
            breg1 = *(const f32x4*)(bptr + 16);                                \
            bptr += 32;                                                        \
        }                                                                      \
    }

    // t = 0: KC=kA, KN=kB, VN=vA, no PV (VC unused -> pass vB)
    BODY(kA0, kA1, kA2, kA3, kB0, kB1, kB2, kB3,
         vB0, vB1, vB2, vB3, vA0, vA1, vA2, vA3, true, true, false)
    // t = 1..30: 15 pairs (odd: KC=kB,VC=vA,VN=vB; even: KC=kA,VC=vB,VN=vA)
    for (int i = 0; i < 15; ++i) {
        BODY(kB0, kB1, kB2, kB3, kA0, kA1, kA2, kA3,
             vA0, vA1, vA2, vA3, vB0, vB1, vB2, vB3, true, true, true)
        BODY(kA0, kA1, kA2, kA3, kB0, kB1, kB2, kB3,
             vB0, vB1, vB2, vB3, vA0, vA1, vA2, vA3, true, true, true)
    }
    // t = 31: KC=kB, VC=vA, VN=vB, no K load, no bias
    BODY(kB0, kB1, kB2, kB3, kA0, kA1, kA2, kA3,
         vA0, vA1, vA2, vA3, vB0, vB1, vB2, vB3, false, false, true)
#undef BODY

    // epilogue: PV for tile 31 (V_31 = vB)
#pragma unroll
    for (int s = 0; s < 4; ++s) {
        acc_o[0][s] = MFMA16(vB0, pb_[s].v, acc_o[0][s]);
        acc_o[1][s] = MFMA16(vB1, pb_[s].v, acc_o[1][s]);
        acc_o[2][s] = MFMA16(vB2, pb_[s].v, acc_o[2][s]);
        acc_o[3][s] = MFMA16(vB3, pb_[s].v, acc_o[3][s]);
    }

    // ---- split-K=4 merge: pure add (max-free softmax) ----
    float* mbuf = smem;                        // 3 regions x 4096 fp32
    float* lbuf = smem + 12288;                // 64 rows x 20 fp32 (padded)

    // all waves: psum -> lbuf[row][w*4+quad]
#pragma unroll
    for (int s = 0; s < 4; ++s)
        lbuf[(s * 16 + lm) * 20 + w * 4 + quad] = psum[s];

    if (w != 0) {
        float* ob = mbuf + (w - 1) * 4096;     // 64 q x 64 d fp32
#pragma unroll
        for (int s = 0; s < 4; ++s) {
            const int r = s * 16 + lm;
#pragma unroll
            for (int mt = 0; mt < 4; ++mt) {
                const int sl = (mt * 4 + quad) ^ lm;
                *(f32x4*)(ob + r * 64 + sl * 4) = acc_o[mt][s];
            }
        }
    }
    __syncthreads();
    if (w != 0) return;

#pragma unroll
    for (int s = 0; s < 4; ++s) {
        const int r = s * 16 + lm;
        f32x4 lv = (f32x4){0.f, 0.f, 0.f, 0.f};
#pragma unroll
        for (int j = 0; j < 4; ++j)
            lv += *(const f32x4*)(lbuf + r * 20 + j * 4);
        const float inv = 1.0f / ((lv[0] + lv[1]) + (lv[2] + lv[3]));
#pragma unroll
        for (int mt = 0; mt < 4; ++mt) {
            const int sl = (mt * 4 + quad) ^ lm;
            f32x4 o = acc_o[mt][s];
#pragma unroll
            for (int p = 0; p < 3; ++p)
                o += *(const f32x4*)(mbuf + p * 4096 + r * 64 + sl * 4);
            u16x4 pkv;
#pragma unroll
            for (int r2 = 0; r2 < 4; ++r2)
                pkv[r2] = f2bf(o[r2] * inv);
            *reinterpret_cast<u16x4*>(Ot + (size_t)(q0 + r) * 512 +
                                      hq + mt * 16 + quad * 4) = pkv;
        }
    }
}

// ---------------------------------------------------------------------------
extern "C" void kernel_launch(void* const* d_in, const int* in_sizes, int n_in,
                              void* d_out, int out_size, void* d_ws, size_t ws_size,
                              hipStream_t stream) {
    (void)in_sizes; (void)n_in; (void)out_size; (void)ws_size;
    const float* X   = (const float*)d_in[0];
    const float* qw  = (const float*)d_in[1];
    const float* qb  = (const float*)d_in[2];
    const float* kw  = (const float*)d_in[3];
    const float* kb  = (const float*)d_in[4];
    const float* vw  = (const float*)d_in[5];
    const float* vb  = (const float*)d_in[6];
    const float* pw  = (const float*)d_in[7];
    const float* pb  = (const float*)d_in[8];
    const float* lqw = (const float*)d_in[9];

    const size_t E = (size_t)4096 * 512;
    const size_t WE = (size_t)512 * 512;
    u16* Xt    = (u16*)d_ws;
    u16* Qt    = Xt + E;
    u16* Kimg  = Qt + E;          // 8 heads x 128 tiles x 2048 u16 = E
    u16* Vimg  = Kimg + E;        // same
    u16* Wqkv  = Vimg + E;        // 1536 x 512 stacked
    u16* Wp    = Wqkv + 3 * WE;
    float* lqw2g = (float*)(Wp + WE);   // 4096 fp32, 16B-aligned
    u16* Ot    = Xt;              // reuse (dead after qkv)

    prep<<<dim3(64, 13), dim3(256), 0, stream>>>(X, Xt, qw, kw, vw, pw,
                                                 Wqkv, Wp, lqw, lqw2g);
    qkv_gemm<<<dim3(32, 12), dim3(512), 0, stream>>>(Wqkv, Xt, qb, kb, vb, Qt, Kimg, Vimg);
    flash_attn<<<dim3(512), dim3(256), 0, stream>>>(Qt, Kimg, Vimg, lqw2g, Ot);
    out_gemm<<<dim3(64, 4), dim3(256), 0, stream>>>(Wp, Ot, pb, (float*)d_out);
}

// Round 16
// 77.373 us; speedup vs baseline: 1.0015x; 1.0015x over previous
//
#include <hip/hip_runtime.h>

typedef unsigned short u16;
typedef unsigned int u32;
typedef __bf16 bf16x8 __attribute__((ext_vector_type(8)));
typedef float f32x4 __attribute__((ext_vector_type(4)));
typedef unsigned short u16x4 __attribute__((ext_vector_type(4)));

#define LOG2E 1.4426950408889634f

#if __has_builtin(__builtin_amdgcn_exp2f)
#define EXP2F(x) __builtin_amdgcn_exp2f(x)
#else
#define EXP2F(x) exp2f(x)
#endif

__device__ __forceinline__ u16 f2bf(float f) {
    union { float f; u32 u; } a; a.f = f;
    u32 u = a.u;
    u += 0x7FFFu + ((u >> 16) & 1u);   // RNE (finite inputs)
    return (u16)(u >> 16);
}
__device__ __forceinline__ bf16x8 ldg8(const u16* p) {
    return *reinterpret_cast<const bf16x8*>(p);
}
#if __has_builtin(__builtin_amdgcn_cvt_pk_bf16_f32)
__device__ __forceinline__ u32 pack2(float a, float b) {
    auto r = __builtin_amdgcn_cvt_pk_bf16_f32(a, b);   // v_cvt_pk_bf16_f32
    return __builtin_bit_cast(u32, r);
}
#else
__device__ __forceinline__ u32 pack2(float a, float b) {
    u32 ua = __float_as_uint(a) + 0x8000u;
    u32 ub = __float_as_uint(b) + 0x8000u;
    return __builtin_amdgcn_perm(ub, ua, 0x07060302);
}
#endif
// async global -> LDS, 16 B per lane. LDS dest = wave-uniform base + lane*16.
__device__ __forceinline__ void async16(const void* g, void* l) {
    __builtin_amdgcn_global_load_lds(
        (const __attribute__((address_space(1))) u32*)g,
        (__attribute__((address_space(3))) u32*)l, 16, 0, 0);
}

#define MFMA16(a, b, c) __builtin_amdgcn_mfma_f32_16x16x32_bf16((a), (b), (c), 0, 0, 0)

// ---------------------------------------------------------------------------
// Fused prep (VECTORIZED, R14 post-mortem: X read was the last scalar-load
// kernel — Common-mistake #2). y<8: transpose 64x64 X tile with float4 loads
// (16B/lane, 4 iters) into padded LDS ([64][68] -> aligned u16x4 row writes,
// even-bank 2-way = free), transposed u32-pair stores (128B contiguous per
// half-wave). y 8..11: pack weights (already float4). y==12: lqw*log2e.
// ---------------------------------------------------------------------------
__global__ __launch_bounds__(256) void prep(const float* __restrict__ X,
                                            u16* __restrict__ Xt,
                                            const float* __restrict__ s0,
                                            const float* __restrict__ s1,
                                            const float* __restrict__ s2,
                                            const float* __restrict__ s3,
                                            u16* __restrict__ Wqkv,
                                            u16* __restrict__ Wp,
                                            const float* __restrict__ lqw,
                                            float* __restrict__ lqw2g) {
    __shared__ u16 tile[64][68];   // +4 pad: 8B-aligned u16x4 rows, bank-safe
    const int tid = threadIdx.x;
    const int y = blockIdx.y;

    if (y < 8) {                                  // transpose 64x64 tile
        const int t0 = blockIdx.x * 64;
        const int c0 = y * 64;
#pragma unroll
        for (int i = 0; i < 4; ++i) {
            int idx = tid + i * 256;              // 0..1023
            int r = idx >> 4;                     // channel row 0..63
            int c4 = idx & 15;                    // float4 col
            float4 v = *reinterpret_cast<const float4*>(
                X + (size_t)(c0 + r) * 4096 + t0 + c4 * 4);
            u16x4 o;
            o[0] = f2bf(v.x); o[1] = f2bf(v.y); o[2] = f2bf(v.z); o[3] = f2bf(v.w);
            *reinterpret_cast<u16x4*>(&tile[r][c4 * 4]) = o;
        }
        __syncthreads();
#pragma unroll
        for (int i = 0; i < 8; ++i) {
            int idx = tid + i * 256;              // 0..2047
            int tr = idx >> 5;                    // token 0..63
            int cc2 = idx & 31;                   // channel pair
            u32 pk = (u32)tile[cc2 * 2][tr] | ((u32)tile[cc2 * 2 + 1][tr] << 16);
            *reinterpret_cast<u32*>(Xt + (size_t)(t0 + tr) * 512 + c0 + cc2 * 2) = pk;
        }
    } else if (y < 12) {                          // pack one 512x512 weight
        const int m = y - 8;
        const float* s = (m == 0) ? s0 : (m == 1) ? s1 : (m == 2) ? s2 : s3;
        u16* d = (m == 3) ? Wp : Wqkv + (size_t)m * 262144;
#pragma unroll
        for (int j = 0; j < 4; ++j) {
            int i = blockIdx.x * 1024 + j * 256 + tid;
            float4 v = reinterpret_cast<const float4*>(s)[i];
            u16x4 o;
            o[0] = f2bf(v.x); o[1] = f2bf(v.y); o[2] = f2bf(v.z); o[3] = f2bf(v.w);
            reinterpret_cast<u16x4*>(d)[i] = o;
        }
    } else {                                      // lqw * LOG2E (1024 float4)
        if (blockIdx.x < 4) {
            int i = blockIdx.x * 256 + tid;
            float4 v = reinterpret_cast<const float4*>(lqw)[i];
            v.x *= LOG2E; v.y *= LOG2E; v.z *= LOG2E; v.w *= LOG2E;
            reinterpret_cast<float4*>(lqw2g)[i] = v;
        }
    }
}

// ---------------------------------------------------------------------------
// Fused QKV GEMM, LDS-staged (R13 version, known-good: Qt/Kt token-major,
// V -> frag-major image Vimg[head][tile][fragX][lane][8 u16]).
// ---------------------------------------------------------------------------
__global__ __launch_bounds__(512, 2) void qkv_gemm(const u16* __restrict__ Wqkv,
                                                   const u16* __restrict__ Xt,
                                                   const float* __restrict__ qb,
                                                   const float* __restrict__ kb,
                                                   const float* __restrict__ vb,
                                                   u16* __restrict__ Qt,
                                                   u16* __restrict__ Kt,
                                                   u16* __restrict__ Vimg) {
    __shared__ __align__(16) u16 Al[2][128 * 32];
    __shared__ __align__(16) u16 Bl[2][128 * 32];

    const int tid = threadIdx.x;
    const int w = tid >> 6, lane = tid & 63;
    const int quad = lane >> 4, lm = lane & 15;
    const int wm = w & 1, wn = w >> 1;
    const int n0 = blockIdx.x * 128;
    const int my = blockIdx.y;
    const int m0 = my * 128;

    const int arow = lane >> 2;
    const int sch = (lane & 3) ^ ((lane >> 3) & 3);   // source chunk (XOR on row>>1)
    const u16* agp = Wqkv + (size_t)(m0 + w * 16 + arow) * 512 + sch * 8;
    const u16* bgp = Xt + (size_t)(n0 + w * 16 + arow) * 512 + sch * 8;

    async16(agp, &Al[0][w * 16 * 32]);
    async16(bgp, &Bl[0][w * 16 * 32]);
    agp += 32; bgp += 32;

    const int FOFF = lm * 64 + ((quad ^ ((lm >> 1) & 3)) << 4);

    f32x4 acc[4][2];
#pragma unroll
    for (int mt = 0; mt < 4; ++mt)
#pragma unroll
        for (int bt = 0; bt < 2; ++bt) acc[mt][bt] = (f32x4){0.f, 0.f, 0.f, 0.f};

    __syncthreads();

    for (int s = 0; s < 16; ++s) {
        const int buf = s & 1;
        if (s < 15) {
            async16(agp, &Al[buf ^ 1][w * 16 * 32]);
            async16(bgp, &Bl[buf ^ 1][w * 16 * 32]);
            agp += 32; bgp += 32;
        }
        const char* Ab = (const char*)&Al[buf][0];
        const char* Bb = (const char*)&Bl[buf][0];
        bf16x8 af[4], bfr[2];
#pragma unroll
        for (int mt = 0; mt < 4; ++mt)
            af[mt] = *(const bf16x8*)(Ab + wm * 4096 + mt * 1024 + FOFF);
#pragma unroll
        for (int bt = 0; bt < 2; ++bt)
            bfr[bt] = *(const bf16x8*)(Bb + wn * 2048 + bt * 1024 + FOFF);
#pragma unroll
        for (int mt = 0; mt < 4; ++mt)
#pragma unroll
            for (int bt = 0; bt < 2; ++bt)
                acc[mt][bt] = MFMA16(af[mt], bfr[bt], acc[mt][bt]);
        __syncthreads();
    }

    const int mat = my >> 2;                     // 0=Q, 1=K, 2=V
    const float* bias = (mat == 0) ? qb : (mat == 1) ? kb : vb;
    const int chbase = (my & 3) * 128 + wm * 64 + quad * 4;

    if (mat < 2) {
        u16* out = mat ? Kt : Qt;
        const float sc = mat ? 1.0f : 0.125f * LOG2E;
#pragma unroll
        for (int mt = 0; mt < 4; ++mt) {
            const int ch = chbase + mt * 16;
            float4 bv = *(const float4*)(bias + ch);
            float bvf[4] = {bv.x, bv.y, bv.z, bv.w};
#pragma unroll
            for (int bt = 0; bt < 2; ++bt) {
                int tok = n0 + wn * 32 + bt * 16 + lm;
                u16x4 pk;
#pragma unroll
                for (int r = 0; r < 4; ++r)
                    pk[r] = f2bf((acc[mt][bt][r] + bvf[r]) * sc);
                *(u16x4*)(out + (size_t)tok * 512 + ch) = pk;
            }
        }
    } else {
        // V -> frag-major image (R13-proven)
#pragma unroll
        for (int mt = 0; mt < 4; ++mt) {
            const int ch = chbase + mt * 16;
            float4 bv = *(const float4*)(bias + ch);
            float bvf[4] = {bv.x, bv.y, bv.z, bv.w};
            const int hh = ch >> 6;
            const int D0 = ch & 63;
#pragma unroll
            for (int bt = 0; bt < 2; ++bt) {
                int g = bt * 16 + lm;
                int key2 = 8 * ((g >> 2) & 3) + 4 * ((g >> 4) & 1) + (g & 3);
                int t = (n0 >> 5) + wn;
                int kc = key2 >> 3, ke = key2 & 7;
                u16* vdst = Vimg + (size_t)(hh * 128 + t) * 2048 + ke;
#pragma unroll
                for (int r = 0; r < 4; ++r) {
                    int D = D0 + r;
                    int lane_i = kc * 16 + ((D >> 1) & 7) * 2 + (D & 1);
                    vdst[(size_t)(D >> 4) * 512 + lane_i * 8] = f2bf(acc[mt][bt][r] + bvf[r]);
                }
            }
        }
    }
}

// ---------------------------------------------------------------------------
// Output projection, LDS-staged (unchanged, known-good).
// ---------------------------------------------------------------------------
__global__ __launch_bounds__(256, 2) void out_gemm(const u16* __restrict__ Wp,
                                                   const u16* __restrict__ Ot,
                                                   const float* __restrict__ pb,
                                                   float* __restrict__ out) {
    __shared__ __align__(16) u16 Al[2][128 * 32];
    __shared__ __align__(16) u16 Bl[2][64 * 32];

    const int tid = threadIdx.x;
    const int w = tid >> 6, lane = tid & 63;
    const int quad = lane >> 4, lm = lane & 15;
    const int wm = w & 1, wn = w >> 1;
    const int n0 = blockIdx.x * 64;
    const int m0 = blockIdx.y * 128;

    const int arow = lane >> 2;
    const int sch = (lane & 3) ^ ((lane >> 3) & 3);
    const u16* agp0 = Wp + (size_t)(m0 + w * 16 + arow) * 512 + sch * 8;
    const u16* agp1 = agp0 + (size_t)64 * 512;
    const u16* bgp = Ot + (size_t)(n0 + w * 16 + arow) * 512 + sch * 8;

    async16(agp0, &Al[0][w * 16 * 32]);
    async16(agp1, &Al[0][(64 + w * 16) * 32]);
    async16(bgp, &Bl[0][w * 16 * 32]);
    agp0 += 32; agp1 += 32; bgp += 32;

    const int FOFF = lm * 64 + ((quad ^ ((lm >> 1) & 3)) << 4);

    f32x4 acc[4][2];
#pragma unroll
    for (int mt = 0; mt < 4; ++mt)
#pragma unroll
        for (int bt = 0; bt < 2; ++bt) acc[mt][bt] = (f32x4){0.f, 0.f, 0.f, 0.f};

    __syncthreads();

    for (int s = 0; s < 16; ++s) {
        const int buf = s & 1;
        if (s < 15) {
            async16(agp0, &Al[buf ^ 1][w * 16 * 32]);
            async16(agp1, &Al[buf ^ 1][(64 + w * 16) * 32]);
            async16(bgp, &Bl[buf ^ 1][w * 16 * 32]);
            agp0 += 32; agp1 += 32; bgp += 32;
        }
        const char* Ab = (const char*)&Al[buf][0];
        const char* Bb = (const char*)&Bl[buf][0];
        bf16x8 af[4], bfr[2];
#pragma unroll
        for (int mt = 0; mt < 4; ++mt)
            af[mt] = *(const bf16x8*)(Ab + wm * 4096 + mt * 1024 + FOFF);
#pragma unroll
        for (int bt = 0; bt < 2; ++bt)
            bfr[bt] = *(const bf16x8*)(Bb + wn * 2048 + bt * 1024 + FOFF);
#pragma unroll
        for (int mt = 0; mt < 4; ++mt)
#pragma unroll
            for (int bt = 0; bt < 2; ++bt)
                acc[mt][bt] = MFMA16(af[mt], bfr[bt], acc[mt][bt]);
        __syncthreads();
    }

#pragma unroll
    for (int mt = 0; mt < 4; ++mt) {
        const int ch = m0 + wm * 64 + mt * 16 + quad * 4;
        float4 bv = *(const float4*)(pb + ch);
        float bvf[4] = {bv.x, bv.y, bv.z, bv.w};
#pragma unroll
        for (int bt = 0; bt < 2; ++bt) {
            int tok = n0 + wn * 32 + bt * 16 + lm;
#pragma unroll
            for (int r = 0; r < 4; ++r)
                out[(size_t)(ch + r) * 4096 + tok] = acc[mt][bt][r] + bvf[r];
        }
    }
}

// ---------------------------------------------------------------------------
// Flash attention (R13 best: 44.5 us): K async-staged into private LDS dbuf,
// V streamed from frag-major image via coalesced 1KB ldg8, in-body pipeline
// carry (pv=nv), barrier-free main loop, head-clustered grid, split-K=4
// merge. UNCHANGED from R13 — four structurally different variants all land
// 44.5-48.5 us (local minimum of this design family; HK-class structure
// would be needed for more).
// ---------------------------------------------------------------------------
#define WAITVM(N) asm volatile("s_waitcnt vmcnt(" #N ")" ::: "memory")

__global__ __launch_bounds__(256, 2) void flash_attn(const u16* __restrict__ Qt,
                                                     const u16* __restrict__ Kt,
                                                     const u16* __restrict__ Vimg,
                                                     const float* __restrict__ lqw2g,
                                                     u16* __restrict__ Ot) {
    __shared__ __align__(16) char smem[65536];

    const int tid = threadIdx.x;
    const int w = tid >> 6, lane = tid & 63;         // w = 0..3 (key quarter)
    const int quad = lane >> 4, lm = lane & 15;
    const int bid = blockIdx.x;
    const int h = bid & 7, hq = h * 64;              // head -> XCD cluster
    const int q0 = (bid >> 3) * 64;
    const int kstart = w * 1024;

    char* kvw = smem + w * 8192;                     // private K dbuf (2 x 4 KB)

    // K staging (XOR swizzle at global source, LDS linear)
    const int srow = lane >> 3;                      // 0..7
    const int schunk = (lane & 7) ^ srow;
    const u16* kg = Kt + (size_t)(kstart + srow) * 512 + hq + schunk * 8;

    // V frag-major image: tile = 2048 u16; frag X at +X*512; lane at +lane*8
    const u16* vp = Vimg + (size_t)(h * 128 + w * 32) * 2048 + (size_t)lane * 8;

    // Q fragments: 4 subtiles x 2 d-halves (8 vmem loads)
    bf16x8 bq0[4], bq1[4];
#pragma unroll
    for (int s = 0; s < 4; ++s) {
        const u16* qb = Qt + (size_t)(q0 + s * 16 + lm) * 512 + hq + quad * 8;
        bq0[s] = ldg8(qb);
        bq1[s] = ldg8(qb + 32);
    }

    // bias prefetch registers (2 vmem loads)
    f32x4 breg0 = *(const f32x4*)(lqw2g + kstart + quad * 4);
    f32x4 breg1 = *(const f32x4*)(lqw2g + kstart + 16 + quad * 4);
    const float* bptr = lqw2g + kstart + 32 + quad * 4;

    // K fragment read offsets (proven layout)
    const int A0 = lm * 128 + ((quad ^ (lm & 7)) << 4);       // d 0..31
    const int A1 = A0 ^ 64;                                   // d 32..63

#define STAGEK(DST)                                                            \
    {                                                                          \
        char* nb = (DST);                                                      \
        async16(kg, nb);                                                       \
        async16(kg + 8 * 512, nb + 1024);                                      \
        async16(kg + 16 * 512, nb + 2048);                                     \
        async16(kg + 24 * 512, nb + 3072);                                     \
        kg += 32 * 512;                                                        \
    }

    // stage K tiles 0 and 1
    STAGEK(kvw)
    STAGEK(kvw + 4096)

    union { u32 u[4]; bf16x8 v; } onesu;
    onesu.u[0] = onesu.u[1] = onesu.u[2] = onesu.u[3] = 0x3F803F80u;
    const bf16x8 onesv = onesu.v;

    f32x4 acc_o[4][4];                                // [d-group][q-sub]
#pragma unroll
    for (int mt = 0; mt < 4; ++mt)
#pragma unroll
        for (int s = 0; s < 4; ++s) acc_o[mt][s] = (f32x4){0.f, 0.f, 0.f, 0.f};
    f32x4 acc_l[4];
#pragma unroll
    for (int s = 0; s < 4; ++s) acc_l[s] = (f32x4){0.f, 0.f, 0.f, 0.f};

    // loop-carried pipeline state: P (bb) and V frags of the previous tile
    union { u32 u[4]; bf16x8 v; } pb_[4];
    bf16x8 pv0, pv1, pv2, pv3;
    int bufsel = 0;

#define BODY(WN, DOBIAS, DOSTAGE, DOPV)                                        \
    {                                                                          \
        WAITVM(WN);                                                            \
        bf16x8 nv0 = ldg8(vp);                                                 \
        bf16x8 nv1 = ldg8(vp + 512);                                           \
        bf16x8 nv2 = ldg8(vp + 1024);                                          \
        bf16x8 nv3 = ldg8(vp + 1536);                                          \
        vp += 2048;                                                            \
        const char* Kb = kvw + bufsel;                                         \
        bf16x8 k00 = *(const bf16x8*)(Kb + A0);                                \
        bf16x8 k01 = *(const bf16x8*)(Kb + A1);                                \
        bf16x8 k10 = *(const bf16x8*)(Kb + 2048 + A0);                         \
        bf16x8 k11 = *(const bf16x8*)(Kb + 2048 + A1);                         \
        if (DOPV) {                                                            \
            _Pragma("unroll")                                                  \
            for (int s = 0; s < 4; ++s) {                                      \
                acc_o[0][s] = MFMA16(pv0, pb_[s].v, acc_o[0][s]);              \
                acc_o[1][s] = MFMA16(pv1, pb_[s].v, acc_o[1][s]);              \
                acc_o[2][s] = MFMA16(pv2, pb_[s].v, acc_o[2][s]);              \
                acc_o[3][s] = MFMA16(pv3, pb_[s].v, acc_o[3][s]);              \
                acc_l[s] = MFMA16(onesv, pb_[s].v, acc_l[s]);                  \
            }                                                                  \
        }                                                                      \
        _Pragma("unroll")                                                      \
        for (int s = 0; s < 4; ++s) {                                          \
            f32x4 a = MFMA16(k00, bq0[s], breg0);                              \
            a = MFMA16(k01, bq1[s], a);                                        \
            pb_[s].u[0] = pack2(EXP2F(a[0]), EXP2F(a[1]));                     \
            pb_[s].u[1] = pack2(EXP2F(a[2]), EXP2F(a[3]));                     \
        }                                                                      \
        _Pragma("unroll")                                                      \
        for (int s = 0; s < 4; ++s) {                                          \
            f32x4 c = MFMA16(k10, bq0[s], breg1);                              \
            c = MFMA16(k11, bq1[s], c);                                        \
            pb_[s].u[2] = pack2(EXP2F(c[0]), EXP2F(c[1]));                     \
            pb_[s].u[3] = pack2(EXP2F(c[2]), EXP2F(c[3]));                     \
        }                                                                      \
        if (DOBIAS) {                                                          \
            breg0 = *(const f32x4*)(bptr);                                     \
            breg1 = *(const f32x4*)(bptr + 16);                                \
            bptr += 32;                                                        \
        }                                                                      \
        pv0 = nv0; pv1 = nv1; pv2 = nv2; pv3 = nv3;                            \
        if (DOSTAGE) STAGEK(kvw + bufsel)                                      \
        bufsel ^= 4096;                                                        \
    }

    BODY(4, true, true, false)                 // t = 0: QK only (peel)
    for (int t = 1; t < 30; ++t)
        BODY(10, true, true, true)             // t = 1..29: PV_{t-1} + QK_t
    BODY(6, true, false, true)                 // t = 30 (bias_31, no stage)
    BODY(2, false, false, true)                // t = 31

#undef BODY
#undef STAGEK

    // epilogue: PV for tile 31
#pragma unroll
    for (int s = 0; s < 4; ++s) {
        acc_o[0][s] = MFMA16(pv0, pb_[s].v, acc_o[0][s]);
        acc_o[1][s] = MFMA16(pv1, pb_[s].v, acc_o[1][s]);
        acc_o[2][s] = MFMA16(pv2, pb_[s].v, acc_o[2][s]);
        acc_o[3][s] = MFMA16(pv3, pb_[s].v, acc_o[3][s]);
        acc_l[s] = MFMA16(onesv, pb_[s].v, acc_l[s]);
    }

    // ---- split-K merge: pure add (max-free softmax), 4-way ----
    __syncthreads();                           // staging LDS now dead
    float* mbuf = (float*)smem;
    if (w != 0) {
        float* ob = mbuf + (w - 1) * 4096;     // 64 q x 64 d fp32
#pragma unroll
        for (int s = 0; s < 4; ++s) {
            const int r = s * 16 + lm;
#pragma unroll
            for (int mt = 0; mt < 4; ++mt) {
                const int sl = (mt * 4 + quad) ^ lm;
                *(f32x4*)(ob + r * 64 + sl * 4) = acc_o[mt][s];
            }
        }
        if (quad == 0) {
#pragma unroll
            for (int s = 0; s < 4; ++s)
                mbuf[12288 + (w - 1) * 64 + s * 16 + lm] = acc_l[s][0];
        }
    }
    __syncthreads();
    if (w != 0) return;

#pragma unroll
    for (int s = 0; s < 4; ++s) {
        const int r = s * 16 + lm;
        float lsum = acc_l[s][0];
#pragma unroll
        for (int p = 0; p < 3; ++p)
            lsum += mbuf[12288 + p * 64 + r];
        const float inv = 1.0f / lsum;
#pragma unroll
        for (int mt = 0; mt < 4; ++mt) {
            const int sl = (mt * 4 + quad) ^ lm;
            f32x4 o = acc_o[mt][s];
#pragma unroll
            for (int p = 0; p < 3; ++p)
                o += *(const f32x4*)(mbuf + p * 4096 + r * 64 + sl * 4);
            u16x4 pkv;
#pragma unroll
            for (int r2 = 0; r2 < 4; ++r2)
                pkv[r2] = f2bf(o[r2] * inv);
            *reinterpret_cast<u16x4*>(Ot + (size_t)(q0 + r) * 512 +
                                      hq + mt * 16 + quad * 4) = pkv;
        }
    }
}

// ---------------------------------------------------------------------------
extern "C" void kernel_launch(void* const* d_in, const int* in_sizes, int n_in,
                              void* d_out, int out_size, void* d_ws, size_t ws_size,
                              hipStream_t stream) {
    (void)in_sizes; (void)n_in; (void)out_size; (void)ws_size;
    const float* X   = (const float*)d_in[0];
    const float* qw  = (const float*)d_in[1];
    const float* qb  = (const float*)d_in[2];
    const float* kw  = (const float*)d_in[3];
    const float* kb  = (const float*)d_in[4];
    const float* vw  = (const float*)d_in[5];
    const float* vb  = (const float*)d_in[6];
    const float* pw  = (const float*)d_in[7];
    const float* pb  = (const float*)d_in[8];
    const float* lqw = (const float*)d_in[9];

    const size_t E = (size_t)4096 * 512;
    const size_t WE = (size_t)512 * 512;
    u16* Xt    = (u16*)d_ws;
    u16* Qt    = Xt + E;
    u16* Kt    = Qt + E;
    u16* Vimg  = Kt + E;          // 8 heads x 128 tiles x 2048 u16 = E
    u16* Wqkv  = Vimg + E;        // 1536 x 512 stacked
    u16* Wp    = Wqkv + 3 * WE;
    float* lqw2g = (float*)(Wp + WE);   // 4096 fp32, 16B-aligned
    u16* Ot    = Xt;              // reuse (dead after qkv)

    prep<<<dim3(64, 13), dim3(256), 0, stream>>>(X, Xt, qw, kw, vw, pw,
                                                 Wqkv, Wp, lqw, lqw2g);
    qkv_gemm<<<dim3(32, 12), dim3(512), 0, stream>>>(Wqkv, Xt, qb, kb, vb, Qt, Kt, Vimg);
    flash_attn<<<dim3(512), dim3(256), 0, stream>>>(Qt, Kt, Vimg, lqw2g, Ot);
    out_gemm<<<dim3(64, 4), dim3(256), 0, stream>>>(Wp, Ot, pb, (float*)d_out);
}

// Round 18
// 77.346 us; speedup vs baseline: 1.0019x; 1.0003x over previous
//
#include <hip/hip_runtime.h>

typedef unsigned short u16;
typedef unsigned int u32;
typedef __bf16 bf16x8 __attribute__((ext_vector_type(8)));
typedef float f32x4 __attribute__((ext_vector_type(4)));
typedef unsigned short u16x4 __attribute__((ext_vector_type(4)));

#define LOG2E 1.4426950408889634f

#if __has_builtin(__builtin_amdgcn_exp2f)
#define EXP2F(x) __builtin_amdgcn_exp2f(x)
#else
#define EXP2F(x) exp2f(x)
#endif

__device__ __forceinline__ u16 f2bf(float f) {
    union { float f; u32 u; } a; a.f = f;
    u32 u = a.u;
    u += 0x7FFFu + ((u >> 16) & 1u);   // RNE (finite inputs)
    return (u16)(u >> 16);
}
__device__ __forceinline__ bf16x8 ldg8(const u16* p) {
    return *reinterpret_cast<const bf16x8*>(p);
}
#if __has_builtin(__builtin_amdgcn_cvt_pk_bf16_f32)
__device__ __forceinline__ u32 pack2(float a, float b) {
    auto r = __builtin_amdgcn_cvt_pk_bf16_f32(a, b);   // v_cvt_pk_bf16_f32
    return __builtin_bit_cast(u32, r);
}
#else
__device__ __forceinline__ u32 pack2(float a, float b) {
    u32 ua = __float_as_uint(a) + 0x8000u;
    u32 ub = __float_as_uint(b) + 0x8000u;
    return __builtin_amdgcn_perm(ub, ua, 0x07060302);
}
#endif
// async global -> LDS, 16 B per lane. LDS dest = wave-uniform base + lane*16.
__device__ __forceinline__ void async16(const void* g, void* l) {
    __builtin_amdgcn_global_load_lds(
        (const __attribute__((address_space(1))) u32*)g,
        (__attribute__((address_space(3))) u32*)l, 16, 0, 0);
}

#define MFMA16(a, b, c) __builtin_amdgcn_mfma_f32_16x16x32_bf16((a), (b), (c), 0, 0, 0)

// ---------------------------------------------------------------------------
// Fused prep (vectorized, R16 version — known-good).
// ---------------------------------------------------------------------------
__global__ __launch_bounds__(256) void prep(const float* __restrict__ X,
                                            u16* __restrict__ Xt,
                                            const float* __restrict__ s0,
                                            const float* __restrict__ s1,
                                            const float* __restrict__ s2,
                                            const float* __restrict__ s3,
                                            u16* __restrict__ Wqkv,
                                            u16* __restrict__ Wp,
                                            const float* __restrict__ lqw,
                                            float* __restrict__ lqw2g) {
    __shared__ u16 tile[64][68];   // +4 pad: 8B-aligned u16x4 rows, bank-safe
    const int tid = threadIdx.x;
    const int y = blockIdx.y;

    if (y < 8) {                                  // transpose 64x64 tile
        const int t0 = blockIdx.x * 64;
        const int c0 = y * 64;
#pragma unroll
        for (int i = 0; i < 4; ++i) {
            int idx = tid + i * 256;              // 0..1023
            int r = idx >> 4;                     // channel row 0..63
            int c4 = idx & 15;                    // float4 col
            float4 v = *reinterpret_cast<const float4*>(
                X + (size_t)(c0 + r) * 4096 + t0 + c4 * 4);
            u16x4 o;
            o[0] = f2bf(v.x); o[1] = f2bf(v.y); o[2] = f2bf(v.z); o[3] = f2bf(v.w);
            *reinterpret_cast<u16x4*>(&tile[r][c4 * 4]) = o;
        }
        __syncthreads();
#pragma unroll
        for (int i = 0; i < 8; ++i) {
            int idx = tid + i * 256;              // 0..2047
            int tr = idx >> 5;                    // token 0..63
            int cc2 = idx & 31;                   // channel pair
            u32 pk = (u32)tile[cc2 * 2][tr] | ((u32)tile[cc2 * 2 + 1][tr] << 16);
            *reinterpret_cast<u32*>(Xt + (size_t)(t0 + tr) * 512 + c0 + cc2 * 2) = pk;
        }
    } else if (y < 12) {                          // pack one 512x512 weight
        const int m = y - 8;
        const float* s = (m == 0) ? s0 : (m == 1) ? s1 : (m == 2) ? s2 : s3;
        u16* d = (m == 3) ? Wp : Wqkv + (size_t)m * 262144;
#pragma unroll
        for (int j = 0; j < 4; ++j) {
            int i = blockIdx.x * 1024 + j * 256 + tid;
            float4 v = reinterpret_cast<const float4*>(s)[i];
            u16x4 o;
            o[0] = f2bf(v.x); o[1] = f2bf(v.y); o[2] = f2bf(v.z); o[3] = f2bf(v.w);
            reinterpret_cast<u16x4*>(d)[i] = o;
        }
    } else {                                      // lqw * LOG2E (1024 float4)
        if (blockIdx.x < 4) {
            int i = blockIdx.x * 256 + tid;
            float4 v = reinterpret_cast<const float4*>(lqw)[i];
            v.x *= LOG2E; v.y *= LOG2E; v.z *= LOG2E; v.w *= LOG2E;
            reinterpret_cast<float4*>(lqw2g)[i] = v;
        }
    }
}

// ---------------------------------------------------------------------------
// Fused QKV GEMM, LDS-staged (R13 version, known-good: Qt/Kt token-major,
// V -> frag-major image Vimg[head][tile][fragX][lane][8 u16]).
// ---------------------------------------------------------------------------
__global__ __launch_bounds__(512, 2) void qkv_gemm(const u16* __restrict__ Wqkv,
                                                   const u16* __restrict__ Xt,
                                                   const float* __restrict__ qb,
                                                   const float* __restrict__ kb,
                                                   const float* __restrict__ vb,
                                                   u16* __restrict__ Qt,
                                                   u16* __restrict__ Kt,
                                                   u16* __restrict__ Vimg) {
    __shared__ __align__(16) u16 Al[2][128 * 32];
    __shared__ __align__(16) u16 Bl[2][128 * 32];

    const int tid = threadIdx.x;
    const int w = tid >> 6, lane = tid & 63;
    const int quad = lane >> 4, lm = lane & 15;
    const int wm = w & 1, wn = w >> 1;
    const int n0 = blockIdx.x * 128;
    const int my = blockIdx.y;
    const int m0 = my * 128;

    const int arow = lane >> 2;
    const int sch = (lane & 3) ^ ((lane >> 3) & 3);   // source chunk (XOR on row>>1)
    const u16* agp = Wqkv + (size_t)(m0 + w * 16 + arow) * 512 + sch * 8;
    const u16* bgp = Xt + (size_t)(n0 + w * 16 + arow) * 512 + sch * 8;

    async16(agp, &Al[0][w * 16 * 32]);
    async16(bgp, &Bl[0][w * 16 * 32]);
    agp += 32; bgp += 32;

    const int FOFF = lm * 64 + ((quad ^ ((lm >> 1) & 3)) << 4);

    f32x4 acc[4][2];
#pragma unroll
    for (int mt = 0; mt < 4; ++mt)
#pragma unroll
        for (int bt = 0; bt < 2; ++bt) acc[mt][bt] = (f32x4){0.f, 0.f, 0.f, 0.f};

    __syncthreads();

    for (int s = 0; s < 16; ++s) {
        const int buf = s & 1;
        if (s < 15) {
            async16(agp, &Al[buf ^ 1][w * 16 * 32]);
            async16(bgp, &Bl[buf ^ 1][w * 16 * 32]);
            agp += 32; bgp += 32;
        }
        const char* Ab = (const char*)&Al[buf][0];
        const char* Bb = (const char*)&Bl[buf][0];
        bf16x8 af[4], bfr[2];
#pragma unroll
        for (int mt = 0; mt < 4; ++mt)
            af[mt] = *(const bf16x8*)(Ab + wm * 4096 + mt * 1024 + FOFF);
#pragma unroll
        for (int bt = 0; bt < 2; ++bt)
            bfr[bt] = *(const bf16x8*)(Bb + wn * 2048 + bt * 1024 + FOFF);
#pragma unroll
        for (int mt = 0; mt < 4; ++mt)
#pragma unroll
            for (int bt = 0; bt < 2; ++bt)
                acc[mt][bt] = MFMA16(af[mt], bfr[bt], acc[mt][bt]);
        __syncthreads();
    }

    const int mat = my >> 2;                     // 0=Q, 1=K, 2=V
    const float* bias = (mat == 0) ? qb : (mat == 1) ? kb : vb;
    const int chbase = (my & 3) * 128 + wm * 64 + quad * 4;

    if (mat < 2) {
        u16* out = mat ? Kt : Qt;
        const float sc = mat ? 1.0f : 0.125f * LOG2E;
#pragma unroll
        for (int mt = 0; mt < 4; ++mt) {
            const int ch = chbase + mt * 16;
            float4 bv = *(const float4*)(bias + ch);
            float bvf[4] = {bv.x, bv.y, bv.z, bv.w};
#pragma unroll
            for (int bt = 0; bt < 2; ++bt) {
                int tok = n0 + wn * 32 + bt * 16 + lm;
                u16x4 pk;
#pragma unroll
                for (int r = 0; r < 4; ++r)
                    pk[r] = f2bf((acc[mt][bt][r] + bvf[r]) * sc);
                *(u16x4*)(out + (size_t)tok * 512 + ch) = pk;
            }
        }
    } else {
        // V -> frag-major image (R13-proven)
#pragma unroll
        for (int mt = 0; mt < 4; ++mt) {
            const int ch = chbase + mt * 16;
            float4 bv = *(const float4*)(bias + ch);
            float bvf[4] = {bv.x, bv.y, bv.z, bv.w};
            const int hh = ch >> 6;
            const int D0 = ch & 63;
#pragma unroll
            for (int bt = 0; bt < 2; ++bt) {
                int g = bt * 16 + lm;
                int key2 = 8 * ((g >> 2) & 3) + 4 * ((g >> 4) & 1) + (g & 3);
                int t = (n0 >> 5) + wn;
                int kc = key2 >> 3, ke = key2 & 7;
                u16* vdst = Vimg + (size_t)(hh * 128 + t) * 2048 + ke;
#pragma unroll
                for (int r = 0; r < 4; ++r) {
                    int D = D0 + r;
                    int lane_i = kc * 16 + ((D >> 1) & 7) * 2 + (D & 1);
                    vdst[(size_t)(D >> 4) * 512 + lane_i * 8] = f2bf(acc[mt][bt][r] + bvf[r]);
                }
            }
        }
    }
}

// ---------------------------------------------------------------------------
// Output projection, LDS-staged (unchanged, known-good).
// ---------------------------------------------------------------------------
__global__ __launch_bounds__(256, 2) void out_gemm(const u16* __restrict__ Wp,
                                                   const u16* __restrict__ Ot,
                                                   const float* __restrict__ pb,
                                                   float* __restrict__ out) {
    __shared__ __align__(16) u16 Al[2][128 * 32];
    __shared__ __align__(16) u16 Bl[2][64 * 32];

    const int tid = threadIdx.x;
    const int w = tid >> 6, lane = tid & 63;
    const int quad = lane >> 4, lm = lane & 15;
    const int wm = w & 1, wn = w >> 1;
    const int n0 = blockIdx.x * 64;
    const int m0 = blockIdx.y * 128;

    const int arow = lane >> 2;
    const int sch = (lane & 3) ^ ((lane >> 3) & 3);
    const u16* agp0 = Wp + (size_t)(m0 + w * 16 + arow) * 512 + sch * 8;
    const u16* agp1 = agp0 + (size_t)64 * 512;
    const u16* bgp = Ot + (size_t)(n0 + w * 16 + arow) * 512 + sch * 8;

    async16(agp0, &Al[0][w * 16 * 32]);
    async16(agp1, &Al[0][(64 + w * 16) * 32]);
    async16(bgp, &Bl[0][w * 16 * 32]);
    agp0 += 32; agp1 += 32; bgp += 32;

    const int FOFF = lm * 64 + ((quad ^ ((lm >> 1) & 3)) << 4);

    f32x4 acc[4][2];
#pragma unroll
    for (int mt = 0; mt < 4; ++mt)
#pragma unroll
        for (int bt = 0; bt < 2; ++bt) acc[mt][bt] = (f32x4){0.f, 0.f, 0.f, 0.f};

    __syncthreads();

    for (int s = 0; s < 16; ++s) {
        const int buf = s & 1;
        if (s < 15) {
            async16(agp0, &Al[buf ^ 1][w * 16 * 32]);
            async16(agp1, &Al[buf ^ 1][(64 + w * 16) * 32]);
            async16(bgp, &Bl[buf ^ 1][w * 16 * 32]);
            agp0 += 32; agp1 += 32; bgp += 32;
        }
        const char* Ab = (const char*)&Al[buf][0];
        const char* Bb = (const char*)&Bl[buf][0];
        bf16x8 af[4], bfr[2];
#pragma unroll
        for (int mt = 0; mt < 4; ++mt)
            af[mt] = *(const bf16x8*)(Ab + wm * 4096 + mt * 1024 + FOFF);
#pragma unroll
        for (int bt = 0; bt < 2; ++bt)
            bfr[bt] = *(const bf16x8*)(Bb + wn * 2048 + bt * 1024 + FOFF);
#pragma unroll
        for (int mt = 0; mt < 4; ++mt)
#pragma unroll
            for (int bt = 0; bt < 2; ++bt)
                acc[mt][bt] = MFMA16(af[mt], bfr[bt], acc[mt][bt]);
        __syncthreads();
    }

#pragma unroll
    for (int mt = 0; mt < 4; ++mt) {
        const int ch = m0 + wm * 64 + mt * 16 + quad * 4;
        float4 bv = *(const float4*)(pb + ch);
        float bvf[4] = {bv.x, bv.y, bv.z, bv.w};
#pragma unroll
        for (int bt = 0; bt < 2; ++bt) {
            int tok = n0 + wn * 32 + bt * 16 + lm;
#pragma unroll
            for (int r = 0; r < 4; ++r)
                out[(size_t)(ch + r) * 4096 + tok] = acc[mt][bt][r] + bvf[r];
        }
    }
}

// ---------------------------------------------------------------------------
// Flash attention (R13 structure) with LDS SHRUNK TO 50,176 B.
// Actual LDS need is 49,920 B (32 KB K staging overlapped by the 48.75 KB
// merge buffer); declared 64 KB previously capped occupancy at 2 blocks/CU.
// 3 x 50,176 = 150 KB <= 160 KB -> 3 blocks/CU becomes LDS-feasible.
// Registers ~168 unified <= 170 (512/3 per SIMD) — knife-edge, but
// launch_bounds stays (256,2): no forced cap. If it fits, HW runs 3
// blocks/CU (+50% waves/SIMD at IDENTICAL traffic — the one occupancy
// experiment not yet isolated); if not, runs 2 and nothing regresses.
// Everything else byte-identical to the verified R16 build (77.37 us).
// ---------------------------------------------------------------------------
#define WAITVM(N) asm volatile("s_waitcnt vmcnt(" #N ")" ::: "memory")

__global__ __launch_bounds__(256, 2) void flash_attn(const u16* __restrict__ Qt,
                                                     const u16* __restrict__ Kt,
                                                     const u16* __restrict__ Vimg,
                                                     const float* __restrict__ lqw2g,
                                                     u16* __restrict__ Ot) {
    __shared__ __align__(16) char smem[50176];   // 49,920 B used (staging 32K overlapped)

    const int tid = threadIdx.x;
    const int w = tid >> 6, lane = tid & 63;         // w = 0..3 (key quarter)
    const int quad = lane >> 4, lm = lane & 15;
    const int bid = blockIdx.x;
    const int h = bid & 7, hq = h * 64;              // head -> XCD cluster
    const int q0 = (bid >> 3) * 64;
    const int kstart = w * 1024;

    char* kvw = smem + w * 8192;                     // private K dbuf (2 x 4 KB)

    // K staging (XOR swizzle at global source, LDS linear)
    const int srow = lane >> 3;                      // 0..7
    const int schunk = (lane & 7) ^ srow;
    const u16* kg = Kt + (size_t)(kstart + srow) * 512 + hq + schunk * 8;

    // V frag-major image: tile = 2048 u16; frag X at +X*512; lane at +lane*8
    const u16* vp = Vimg + (size_t)(h * 128 + w * 32) * 2048 + (size_t)lane * 8;

    // Q fragments: 4 subtiles x 2 d-halves (8 vmem loads)
    bf16x8 bq0[4], bq1[4];
#pragma unroll
    for (int s = 0; s < 4; ++s) {
        const u16* qb = Qt + (size_t)(q0 + s * 16 + lm) * 512 + hq + quad * 8;
        bq0[s] = ldg8(qb);
        bq1[s] = ldg8(qb + 32);
    }

    // bias prefetch registers (2 vmem loads)
    f32x4 breg0 = *(const f32x4*)(lqw2g + kstart + quad * 4);
    f32x4 breg1 = *(const f32x4*)(lqw2g + kstart + 16 + quad * 4);
    const float* bptr = lqw2g + kstart + 32 + quad * 4;

    // K fragment read offsets (proven layout)
    const int A0 = lm * 128 + ((quad ^ (lm & 7)) << 4);       // d 0..31
    const int A1 = A0 ^ 64;                                   // d 32..63

#define STAGEK(DST)                                                            \
    {                                                                          \
        char* nb = (DST);                                                      \
        async16(kg, nb);                                                       \
        async16(kg + 8 * 512, nb + 1024);                                      \
        async16(kg + 16 * 512, nb + 2048);                                     \
        async16(kg + 24 * 512, nb + 3072);                                     \
        kg += 32 * 512;                                                        \
    }

    // stage K tiles 0 and 1
    STAGEK(kvw)
    STAGEK(kvw + 4096)

    union { u32 u[4]; bf16x8 v; } onesu;
    onesu.u[0] = onesu.u[1] = onesu.u[2] = onesu.u[3] = 0x3F803F80u;
    const bf16x8 onesv = onesu.v;

    f32x4 acc_o[4][4];                                // [d-group][q-sub]
#pragma unroll
    for (int mt = 0; mt < 4; ++mt)
#pragma unroll
        for (int s = 0; s < 4; ++s) acc_o[mt][s] = (f32x4){0.f, 0.f, 0.f, 0.f};
    f32x4 acc_l[4];
#pragma unroll
    for (int s = 0; s < 4; ++s) acc_l[s] = (f32x4){0.f, 0.f, 0.f, 0.f};

    // loop-carried pipeline state: P (bb) and V frags of the previous tile
    union { u32 u[4]; bf16x8 v; } pb_[4];
    bf16x8 pv0, pv1, pv2, pv3;
    int bufsel = 0;

#define BODY(WN, DOBIAS, DOSTAGE, DOPV)                                        \
    {                                                                          \
        WAITVM(WN);                                                            \
        bf16x8 nv0 = ldg8(vp);                                                 \
        bf16x8 nv1 = ldg8(vp + 512);                                           \
        bf16x8 nv2 = ldg8(vp + 1024);                                          \
        bf16x8 nv3 = ldg8(vp + 1536);                                          \
        vp += 2048;                                                            \
        const char* Kb = kvw + bufsel;                                         \
        bf16x8 k00 = *(const bf16x8*)(Kb + A0);                                \
        bf16x8 k01 = *(const bf16x8*)(Kb + A1);                                \
        bf16x8 k10 = *(const bf16x8*)(Kb + 2048 + A0);                         \
        bf16x8 k11 = *(const bf16x8*)(Kb + 2048 + A1);                         \
        if (DOPV) {                                                            \
            _Pragma("unroll")                                                  \
            for (int s = 0; s < 4; ++s) {                                      \
                acc_o[0][s] = MFMA16(pv0, pb_[s].v, acc_o[0][s]);              \
                acc_o[1][s] = MFMA16(pv1, pb_[s].v, acc_o[1][s]);              \
                acc_o[2][s] = MFMA16(pv2, pb_[s].v, acc_o[2][s]);              \
                acc_o[3][s] = MFMA16(pv3, pb_[s].v, acc_o[3][s]);              \
                acc_l[s] = MFMA16(onesv, pb_[s].v, acc_l[s]);                  \
            }                                                                  \
        }                                                                      \
        _Pragma("unroll")                                                      \
        for (int s = 0; s < 4; ++s) {                                          \
            f32x4 a = MFMA16(k00, bq0[s], breg0);                              \
            a = MFMA16(k01, bq1[s], a);                                        \
            pb_[s].u[0] = pack2(EXP2F(a[0]), EXP2F(a[1]));                     \
            pb_[s].u[1] = pack2(EXP2F(a[2]), EXP2F(a[3]));                     \
        }                                                                      \
        _Pragma("unroll")                                                      \
        for (int s = 0; s < 4; ++s) {                                          \
            f32x4 c = MFMA16(k10, bq0[s], breg1);                              \
            c = MFMA16(k11, bq1[s], c);                                        \
            pb_[s].u[2] = pack2(EXP2F(c[0]), EXP2F(c[1]));                     \
            pb_[s].u[3] = pack2(EXP2F(c[2]), EXP2F(c[3]));                     \
        }                                                                      \
        if (DOBIAS) {                                                          \
            breg0 = *(const f32x4*)(bptr);                                     \
            breg1 = *(const f32x4*)(bptr + 16);                                \
            bptr += 32;                                                        \
        }                                                                      \
        pv0 = nv0; pv1 = nv1; pv2 = nv2; pv3 = nv3;                            \
        if (DOSTAGE) STAGEK(kvw + bufsel)                                      \
        bufsel ^= 4096;                                                        \
    }

    BODY(4, true, true, false)                 // t = 0: QK only (peel)
    for (int t = 1; t < 30; ++t)
        BODY(10, true, true, true)             // t = 1..29: PV_{t-1} + QK_t
    BODY(6, true, false, true)                 // t = 30 (bias_31, no stage)
    BODY(2, false, false, true)                // t = 31

#undef BODY
#undef STAGEK

    // epilogue: PV for tile 31
#pragma unroll
    for (int s = 0; s < 4; ++s) {
        acc_o[0][s] = MFMA16(pv0, pb_[s].v, acc_o[0][s]);
        acc_o[1][s] = MFMA16(pv1, pb_[s].v, acc_o[1][s]);
        acc_o[2][s] = MFMA16(pv2, pb_[s].v, acc_o[2][s]);
        acc_o[3][s] = MFMA16(pv3, pb_[s].v, acc_o[3][s]);
        acc_l[s] = MFMA16(onesv, pb_[s].v, acc_l[s]);
    }

    // ---- split-K merge: pure add (max-free softmax), 4-way ----
    __syncthreads();                           // staging LDS now dead
    float* mbuf = (float*)smem;
    if (w != 0) {
        float* ob = mbuf + (w - 1) * 4096;     // 64 q x 64 d fp32
#pragma unroll
        for (int s = 0; s < 4; ++s) {
            const int r = s * 16 + lm;
#pragma unroll
            for (int mt = 0; mt < 4; ++mt) {
                const int sl = (mt * 4 + quad) ^ lm;
                *(f32x4*)(ob + r * 64 + sl * 4) = acc_o[mt][s];
            }
        }
        if (quad == 0) {
#pragma unroll
            for (int s = 0; s < 4; ++s)
                mbuf[12288 + (w - 1) * 64 + s * 16 + lm] = acc_l[s][0];
        }
    }
    __syncthreads();
    if (w != 0) return;

#pragma unroll
    for (int s = 0; s < 4; ++s) {
        const int r = s * 16 + lm;
        float lsum = acc_l[s][0];
#pragma unroll
        for (int p = 0; p < 3; ++p)
            lsum += mbuf[12288 + p * 64 + r];
        const float inv = 1.0f / lsum;
#pragma unroll
        for (int mt = 0; mt < 4; ++mt) {
            const int sl = (mt * 4 + quad) ^ lm;
            f32x4 o = acc_o[mt][s];
#pragma unroll
            for (int p = 0; p < 3; ++p)
                o += *(const f32x4*)(mbuf + p * 4096 + r * 64 + sl * 4);
            u16x4 pkv;
#pragma unroll
            for (int r2 = 0; r2 < 4; ++r2)
                pkv[r2] = f2bf(o[r2] * inv);
            *reinterpret_cast<u16x4*>(Ot + (size_t)(q0 + r) * 512 +
                                      hq + mt * 16 + quad * 4) = pkv;
        }
    }
}

// ---------------------------------------------------------------------------
extern "C" void kernel_launch(void* const* d_in, const int* in_sizes, int n_in,
                              void* d_out, int out_size, void* d_ws, size_t ws_size,
                              hipStream_t stream) {
    (void)in_sizes; (void)n_in; (void)out_size; (void)ws_size;
    const float* X   = (const float*)d_in[0];
    const float* qw  = (const float*)d_in[1];
    const float* qb  = (const float*)d_in[2];
    const float* kw  = (const float*)d_in[3];
    const float* kb  = (const float*)d_in[4];
    const float* vw  = (const float*)d_in[5];
    const float* vb  = (const float*)d_in[6];
    const float* pw  = (const float*)d_in[7];
    const float* pb  = (const float*)d_in[8];
    const float* lqw = (const float*)d_in[9];

    const size_t E = (size_t)4096 * 512;
    const size_t WE = (size_t)512 * 512;
    u16* Xt    = (u16*)d_ws;
    u16* Qt    = Xt + E;
    u16* Kt    = Qt + E;
    u16* Vimg  = Kt + E;          // 8 heads x 128 tiles x 2048 u16 = E
    u16* Wqkv  = Vimg + E;        // 1536 x 512 stacked
    u16* Wp    = Wqkv + 3 * WE;
    float* lqw2g = (float*)(Wp + WE);   // 4096 fp32, 16B-aligned
    u16* Ot    = Xt;              // reuse (dead after qkv)

    prep<<<dim3(64, 13), dim3(256), 0, stream>>>(X, Xt, qw, kw, vw, pw,
                                                 Wqkv, Wp, lqw, lqw2g);
    qkv_gemm<<<dim3(32, 12), dim3(512), 0, stream>>>(Wqkv, Xt, qb, kb, vb, Qt, Kt, Vimg);
    flash_attn<<<dim3(512), dim3(256), 0, stream>>>(Qt, Kt, Vimg, lqw2g, Ot);
    out_gemm<<<dim3(64, 4), dim3(256), 0, stream>>>(Wp, Ot, pb, (float*)d_out);
}